// Round 15
// baseline (198.149 us; speedup 1.0000x reference)
//
#include <hip/hip_runtime.h>

#define N_ROWS 65536
#define NE 1024
#define ED 64
#define ERR_GAP 8e-5f

static const size_t OFF_ZQ = 1;
static const size_t OFF_ME = 1 + 4194304;
static const size_t OFF_IDX = OFF_ME + (size_t)N_ROWS * NE;
#define ME_FLOATS ((size_t)N_ROWS * NE)   // 67108864

// scratch now lives in the z_q OUTPUT region (consumed before k_zq overwrites it).
// sbase = out + 4 (16B aligned). Offsets in floats:
#define SC_CBF  0         // cbfrag: 131072 shorts = 65536 floats
#define SC_Z2   65536     // z2: 65536 floats
#define SC_FLAG 131072    // flag: 65536 ints
// d_ws: e2 at +16 (4KB), partial at +4112 (8KB)

typedef __attribute__((ext_vector_type(8))) short short8v;
typedef __attribute__((ext_vector_type(4))) float f32x4;

__device__ __forceinline__ unsigned bf16_rne(float v) {
  unsigned u = __float_as_uint(v);
  return (u + 0x7FFFu + ((u >> 16) & 1u)) >> 16;
}

__device__ __forceinline__ void gld16(const void* g, void* l) {
  __builtin_amdgcn_global_load_lds(
      (const __attribute__((address_space(1))) void*)g,
      (__attribute__((address_space(3))) void*)l, 16, 0, 0);
}

// ---- zero-fill the one-hot region (no ordering deps -> runs first) ----
__global__ __launch_bounds__(256) void k_fill(float* __restrict__ me) {
  const size_t n4 = (ME_FLOATS - 3) >> 2;
  float4* __restrict__ p4 = reinterpret_cast<float4*>(me + 3);
  const size_t stride = (size_t)gridDim.x * blockDim.x;
  const float4 zero4 = make_float4(0.f, 0.f, 0.f, 0.f);
  for (size_t i = blockIdx.x * (size_t)blockDim.x + threadIdx.x; i < n4; i += stride)
    p4[i] = zero4;
  if (blockIdx.x == 0 && threadIdx.x == 0) {
    me[0] = 0.f; me[1] = 0.f; me[2] = 0.f;
    me[ME_FLOATS - 1] = 0.f;
  }
}

// ---- fused: codebook split (B-fragment order) + e2 (bit-exact) ----
__global__ __launch_bounds__(256) void k_e2cb(const float* __restrict__ cb,
                                              float* __restrict__ e2,
                                              short* __restrict__ cbfrag) {
  const int tid = blockIdx.x * 256 + threadIdx.x;
  const int ct = tid >> 6, lane = tid & 63;
  const int col = ct * 16 + (lane & 15);
  const int k0 = (lane >> 4) * 8;
  const float* __restrict__ ep = cb + (size_t)col * ED + k0;
  short* __restrict__ o = cbfrag + (size_t)ct * 2048 + lane * 8;
  #pragma unroll
  for (int ks = 0; ks < 2; ++ks) {
    short h[8], lo[8];
    #pragma unroll
    for (int i = 0; i < 8; ++i) {
      const float v = ep[ks * 32 + i];
      const unsigned hb = bf16_rne(v);
      const float res = v - __uint_as_float(hb << 16);
      h[i] = (short)hb; lo[i] = (short)bf16_rne(res);
    }
    *(short8v*)(o + (size_t)(0 * 2 + ks) * 512) = *(short8v*)h;
    *(short8v*)(o + (size_t)(1 * 2 + ks) * 512) = *(short8v*)lo;
  }
  if (threadIdx.x < 64) {
    const int j = blockIdx.x * 64 + threadIdx.x;
    const float* __restrict__ e = cb + (size_t)j * ED;
    float r[8];
    #pragma unroll
    for (int i = 0; i < 8; ++i) {
      float v = e[i]; float q = v * v;
      asm volatile("" : "+v"(q)); r[i] = q;
    }
    #pragma unroll
    for (int k = 1; k < 8; ++k)
      #pragma unroll
      for (int i = 0; i < 8; ++i) {
        float v = e[8 * k + i]; float q = v * v;
        asm volatile("" : "+v"(q)); r[i] += q;
      }
    e2[j] = ((r[0] + r[1]) + (r[2] + r[3])) + ((r[4] + r[5]) + (r[6] + r[7]));
  }
}

// ---- fused: z stage (LDS) + split-to-regs + z2 + MFMA distance + flags ----
// LDS union: z f32 tile (16.6KB) overlaps lB (32KB); +e2l(4KB)+z2l(256B)=37.1KB.
// All certified arithmetic (split values, z2 pairwise order, MFMA accumulation
// order, epilogue, tie semantics) identical to the r8-r14 passing lineage.
__global__ __launch_bounds__(256, 4) void k_dist(const float* __restrict__ z,
    const short* __restrict__ cbfrag, const float* __restrict__ e2g,
    float* __restrict__ z2g, float* __restrict__ idxf, int* __restrict__ flag) {
  __shared__ float4 smem4[2320];                 // 37120 B
  short* lBs = (short*)smem4;                    // lB[buf] = lBs + buf*8192
  float* e2l = (float*)(smem4 + 2048);           // 4KB at 32768
  float* z2l = (float*)(smem4 + 2304);           // 256B at 36864
  float (*lzf)[65] = (float(*)[65])smem4;        // staging view (overlaps lB)

  const int t = threadIdx.x, w = t >> 6, lane = t & 63;
  const int row0 = blockIdx.x * 64;

  gld16(e2g + w * 256 + lane * 4, e2l + w * 256);

  // stage z f32 tile (zsplit's verified pattern: 2-way alias = free)
  const int rl = w * 16 + (lane & 15);
  const int n0 = row0 + rl;
  const int bb = n0 >> 10, hw = n0 & 1023;
  const float* __restrict__ zp = z + (size_t)bb * 65536 + hw;
  const int k0 = (lane >> 4) * 8;
  #pragma unroll
  for (int ks = 0; ks < 2; ++ks)
    #pragma unroll
    for (int i = 0; i < 8; ++i)
      lzf[ks * 32 + k0 + i][rl] = zp[(size_t)(ks * 32 + k0 + i) << 10];
  __syncthreads();

  // extract A-fragments (bit-identical to k_split_z: same bf16_rne on same f32)
  short8v a[2][2];   // [hl][ks]
  #pragma unroll
  for (int ks = 0; ks < 2; ++ks) {
    short h[8], lo[8];
    #pragma unroll
    for (int i = 0; i < 8; ++i) {
      const float v = lzf[ks * 32 + k0 + i][rl];
      const unsigned hb = bf16_rne(v);
      const float res = v - __uint_as_float(hb << 16);
      h[i] = (short)hb; lo[i] = (short)bf16_rne(res);
    }
    a[0][ks] = *(short8v*)h;
    a[1][ks] = *(short8v*)lo;
  }
  // z2: verbatim numpy pairwise order (rows row0+t)
  if (t < 64) {
    float r[8];
    #pragma unroll
    for (int i = 0; i < 8; ++i) {
      const float v = lzf[i][t];
      float q = v * v; asm volatile("" : "+v"(q)); r[i] = q;
    }
    #pragma unroll
    for (int k = 1; k < 8; ++k)
      #pragma unroll
      for (int i = 0; i < 8; ++i) {
        const float v = lzf[8 * k + i][t];
        float q = v * v; asm volatile("" : "+v"(q)); r[i] += q;
      }
    const float z2v = ((r[0] + r[1]) + (r[2] + r[3])) + ((r[4] + r[5]) + (r[6] + r[7]));
    z2g[row0 + t] = z2v;
    z2l[t] = z2v;
  }
  __syncthreads();   // lzf fully consumed; z2l published; safe to overwrite with lB

  // stage chunk 0 into lB[0]
  #pragma unroll
  for (int i = 0; i < 4; ++i) {
    const int s = w * 4 + i;
    gld16(cbfrag + s * 512 + lane * 8, lBs + s * 512);
  }
  float z2r[4];
  #pragma unroll
  for (int reg = 0; reg < 4; ++reg)
    z2r[reg] = z2l[w * 16 + (lane >> 4) * 4 + reg];
  float Tm[4], Ts[4]; int Tb[4];
  #pragma unroll
  for (int reg = 0; reg < 4; ++reg) { Tm[reg] = 1e30f; Ts[reg] = 1e30f; Tb[reg] = 0; }
  __syncthreads();   // drains vmcnt(0): chunk 0 + e2l ready

  int buf = 0;
  for (int c = 0; c < 16; ++c) {
    if (c < 15) {
      #pragma unroll
      for (int i = 0; i < 4; ++i) {
        const int s = w * 4 + i;
        gld16(cbfrag + (size_t)(c + 1) * 8192 + s * 512 + lane * 8,
              lBs + (buf ^ 1) * 8192 + s * 512);
      }
    }
    #pragma unroll 1
    for (int ctl = 0; ctl < 4; ++ctl) {
      short8v bfr[2][2];   // [hl][ks]
      #pragma unroll
      for (int hl = 0; hl < 2; ++hl)
        #pragma unroll
        for (int ks = 0; ks < 2; ++ks)
          bfr[hl][ks] = *(const short8v*)(lBs + buf * 8192 +
              (ctl * 4 + hl * 2 + ks) * 512 + lane * 8);

      f32x4 acc = (f32x4)(0.0f);
      // pairs (a_hl,b_hl): (h,h) (h,l) (l,h); ks inner — same order as r8-r14
      #pragma unroll
      for (int p = 0; p < 3; ++p) {
        const int pa = (p == 2) ? 1 : 0;
        const int pb = (p == 1) ? 1 : 0;
        #pragma unroll
        for (int ks = 0; ks < 2; ++ks)
          acc = __builtin_amdgcn_mfma_f32_16x16x32_bf16(a[pa][ks], bfr[pb][ks], acc, 0, 0, 0);
      }
      const int j = c * 64 + ctl * 16 + (lane & 15);
      const float e2v = e2l[j];
      #pragma unroll
      for (int reg = 0; reg < 4; ++reg) {
        const float dd = (z2r[reg] + e2v) - 2.0f * acc[reg];
        if (dd < Tm[reg]) { Ts[reg] = Tm[reg]; Tm[reg] = dd; Tb[reg] = j; }
        else { Ts[reg] = fminf(Ts[reg], dd); }
      }
    }
    __syncthreads();
    buf ^= 1;
  }

  #pragma unroll
  for (int reg = 0; reg < 4; ++reg) {
    float m = Tm[reg], s = Ts[reg]; int bi = Tb[reg];
    #pragma unroll
    for (int off = 1; off < 16; off <<= 1) {
      const float om = __shfl_xor(m, off, 64);
      const float os = __shfl_xor(s, off, 64);
      const int   oi = __shfl_xor(bi, off, 64);
      if (om < m || (om == m && oi < bi)) { s = fminf(m, os); m = om; bi = oi; }
      else { s = fminf(s, om); }
    }
    if ((lane & 15) == 0) {
      const int n = row0 + w * 16 + (lane >> 4) * 4 + reg;
      idxf[n] = (float)bi;
      flag[n] = (s - m < ERR_GAP) ? 1 : 0;
    }
  }
}

// ---- exact rescore, block-parallel (r14-proven: no per-thread arrays) ----
__global__ __launch_bounds__(256) void k_exact2(const float* __restrict__ z,
    const float* __restrict__ cb, const float* __restrict__ e2,
    const float* __restrict__ z2g, const int* __restrict__ flag,
    float* __restrict__ idxf) {
  __shared__ float zrow[64];
  __shared__ unsigned long long maskS;
  __shared__ float redM[4];
  __shared__ int   redI[4];
  const int t = threadIdx.x, w = t >> 6, lane = t & 63;
  const int row0 = blockIdx.x * 64;
  if (t < 64) {
    const unsigned long long mk = __ballot(flag[row0 + lane] != 0);
    if (lane == 0) maskS = mk;
  }
  __syncthreads();
  unsigned long long mask = maskS;
  while (mask) {
    const int bit = __ffsll((long long)mask) - 1; mask &= mask - 1;
    const int n = row0 + bit;
    const int b = n >> 10, hw = n & 1023;
    if (t < 64) zrow[t] = z[(size_t)b * 65536 + ((size_t)t << 10) + hw];
    __syncthreads();
    const float z2v = z2g[n];
    const float* __restrict__ e0 = cb + (size_t)t * 256;   // codes 4t..4t+3
    float a0 = 0.f, a1 = 0.f, a2 = 0.f, a3 = 0.f;
    #pragma unroll
    for (int k = 0; k < 64; ++k) {
      const float zk = zrow[k];
      a0 = fmaf(zk, e0[k],       a0);   // sequential chain, k ascending (bit-exact)
      a1 = fmaf(zk, e0[64 + k],  a1);
      a2 = fmaf(zk, e0[128 + k], a2);
      a3 = fmaf(zk, e0[192 + k], a3);
    }
    float bm = 1e30f; int bi = 0;
    const float d0 = (z2v + e2[t * 4 + 0]) - 2.0f * a0;
    const float d1 = (z2v + e2[t * 4 + 1]) - 2.0f * a1;
    const float d2 = (z2v + e2[t * 4 + 2]) - 2.0f * a2;
    const float d3 = (z2v + e2[t * 4 + 3]) - 2.0f * a3;
    if (d0 < bm) { bm = d0; bi = t * 4 + 0; }
    if (d1 < bm) { bm = d1; bi = t * 4 + 1; }
    if (d2 < bm) { bm = d2; bi = t * 4 + 2; }
    if (d3 < bm) { bm = d3; bi = t * 4 + 3; }
    #pragma unroll
    for (int off = 1; off < 64; off <<= 1) {
      const float om = __shfl_xor(bm, off, 64);
      const int   oi = __shfl_xor(bi, off, 64);
      if (om < bm || (om == bm && oi < bi)) { bm = om; bi = oi; }
    }
    if (lane == 0) { redM[w] = bm; redI[w] = bi; }
    __syncthreads();
    if (t == 0) {
      float m = redM[0]; int i0 = redI[0];
      #pragma unroll
      for (int ww = 1; ww < 4; ++ww) {
        if (redM[ww] < m || (redM[ww] == m && redI[ww] < i0)) { m = redM[ww]; i0 = redI[ww]; }
      }
      idxf[n] = (float)i0;
    }
    __syncthreads();
  }
}

// ---- z_q gather + loss partial + fused one-hot scatter ----
__global__ __launch_bounds__(256) void k_zq(const float* __restrict__ z,
    const float* __restrict__ cb, const float* __restrict__ idxf,
    float* __restrict__ zq, float* __restrict__ partial, float* __restrict__ me) {
  float s = 0.f;
  #pragma unroll 1
  for (int it = 0; it < 8; ++it) {
    const int o = (it * 2048 + blockIdx.x) * 256 + threadIdx.x;
    const int b = o >> 16;
    const int d = (o >> 10) & 63;
    const int hw = o & 1023;
    const int n = (b << 10) + hw;
    const int idx = (int)idxf[n];
    const float v = cb[(size_t)idx * ED + d];
    zq[o] = v;
    if (d == 0) me[(size_t)n * NE + idx] = 1.0f;   // fused scatter (once per row)
    const float diff = z[o] - v;
    s = fmaf(diff, diff, s);
  }
  #pragma unroll
  for (int off = 32; off > 0; off >>= 1) s += __shfl_xor(s, off, 64);
  __shared__ float sh[4];
  if ((threadIdx.x & 63) == 0) sh[threadIdx.x >> 6] = s;
  __syncthreads();
  if (threadIdx.x == 0)
    partial[blockIdx.x] = (sh[0] + sh[1]) + (sh[2] + sh[3]);
}

__global__ void k_loss(const float* __restrict__ partial, float* __restrict__ out0) {
  const int t = threadIdx.x;
  double s = 0.0;
  #pragma unroll
  for (int k = 0; k < 8; ++k) s += (double)partial[t + (k << 8)];
  #pragma unroll
  for (int off = 32; off > 0; off >>= 1) s += __shfl_xor(s, off, 64);
  __shared__ double sh[4];
  if ((t & 63) == 0) sh[t >> 6] = s;
  __syncthreads();
  if (t == 0)
    out0[0] = (float)(1.25 * ((sh[0] + sh[1]) + (sh[2] + sh[3])) / 4194304.0);
}

extern "C" void kernel_launch(void* const* d_in, const int* in_sizes, int n_in,
                              void* d_out, int out_size, void* d_ws, size_t ws_size,
                              hipStream_t stream) {
  const float* z  = (const float*)d_in[0];
  const float* cb = (const float*)d_in[1];
  float* out  = (float*)d_out;
  float* zq   = out + OFF_ZQ;
  float* me   = out + OFF_ME;
  float* idxf = out + OFF_IDX;
  float* sbase = out + 4;                    // 16B-aligned scratch in z_q region
  short* cbfrag = (short*)(sbase + SC_CBF);
  float* z2     = sbase + SC_Z2;
  int*   flag   = (int*)(sbase + SC_FLAG);
  float* e2      = (float*)((char*)d_ws + 16);
  float* partial = (float*)((char*)d_ws + 4112);

  k_fill<<<2048, 256, 0, stream>>>(me);                       // no deps, runs first
  k_e2cb<<<16, 256, 0, stream>>>(cb, e2, cbfrag);
  k_dist<<<1024, 256, 0, stream>>>(z, cbfrag, e2, z2, idxf, flag);
  k_exact2<<<1024, 256, 0, stream>>>(z, cb, e2, z2, flag, idxf);
  k_zq<<<2048, 256, 0, stream>>>(z, cb, idxf, zq, partial, me);
  k_loss<<<1, 256, 0, stream>>>(partial, out);
}

// Round 16
// 190.413 us; speedup vs baseline: 1.0406x; 1.0406x over previous
//
#include <hip/hip_runtime.h>

#define N_ROWS 65536
#define NE 1024
#define ED 64
#define ERR_GAP 8e-5f

static const size_t OFF_ZQ = 1;
static const size_t OFF_ME = 1 + 4194304;
static const size_t OFF_IDX = OFF_ME + (size_t)N_ROWS * NE;
#define ME_FLOATS ((size_t)N_ROWS * NE)   // 67108864

// scratch lives in the z_q OUTPUT region (consumed before k_zq overwrites it).
#define SC_CBF  0         // cbfrag: 131072 shorts = 65536 floats
#define SC_Z2   65536     // z2: 65536 floats
#define SC_FLAG 131072    // flag: 65536 ints
// d_ws: e2 at +16 (4KB), partial at +4112 (8KB)

typedef __attribute__((ext_vector_type(8))) short short8v;
typedef __attribute__((ext_vector_type(4))) float f32x4;

__device__ __forceinline__ unsigned bf16_rne(float v) {
  unsigned u = __float_as_uint(v);
  return (u + 0x7FFFu + ((u >> 16) & 1u)) >> 16;
}

__device__ __forceinline__ void gld16(const void* g, void* l) {
  __builtin_amdgcn_global_load_lds(
      (const __attribute__((address_space(1))) void*)g,
      (__attribute__((address_space(3))) void*)l, 16, 0, 0);
}

// ---- zero-fill the one-hot region (no ordering deps -> runs first) ----
__global__ __launch_bounds__(256) void k_fill(float* __restrict__ me) {
  const size_t n4 = (ME_FLOATS - 3) >> 2;
  float4* __restrict__ p4 = reinterpret_cast<float4*>(me + 3);
  const size_t stride = (size_t)gridDim.x * blockDim.x;
  const float4 zero4 = make_float4(0.f, 0.f, 0.f, 0.f);
  for (size_t i = blockIdx.x * (size_t)blockDim.x + threadIdx.x; i < n4; i += stride)
    p4[i] = zero4;
  if (blockIdx.x == 0 && threadIdx.x == 0) {
    me[0] = 0.f; me[1] = 0.f; me[2] = 0.f;
    me[ME_FLOATS - 1] = 0.f;
  }
}

// ---- fused: codebook split (B-fragment order) + e2 (bit-exact) ----
__global__ __launch_bounds__(256) void k_e2cb(const float* __restrict__ cb,
                                              float* __restrict__ e2,
                                              short* __restrict__ cbfrag) {
  const int tid = blockIdx.x * 256 + threadIdx.x;
  const int ct = tid >> 6, lane = tid & 63;
  const int col = ct * 16 + (lane & 15);
  const int k0 = (lane >> 4) * 8;
  const float* __restrict__ ep = cb + (size_t)col * ED + k0;
  short* __restrict__ o = cbfrag + (size_t)ct * 2048 + lane * 8;
  #pragma unroll
  for (int ks = 0; ks < 2; ++ks) {
    short h[8], lo[8];
    #pragma unroll
    for (int i = 0; i < 8; ++i) {
      const float v = ep[ks * 32 + i];
      const unsigned hb = bf16_rne(v);
      const float res = v - __uint_as_float(hb << 16);
      h[i] = (short)hb; lo[i] = (short)bf16_rne(res);
    }
    *(short8v*)(o + (size_t)(0 * 2 + ks) * 512) = *(short8v*)h;
    *(short8v*)(o + (size_t)(1 * 2 + ks) * 512) = *(short8v*)lo;
  }
  if (threadIdx.x < 64) {
    const int j = blockIdx.x * 64 + threadIdx.x;
    const float* __restrict__ e = cb + (size_t)j * ED;
    float r[8];
    #pragma unroll
    for (int i = 0; i < 8; ++i) {
      float v = e[i]; float q = v * v;
      asm volatile("" : "+v"(q)); r[i] = q;
    }
    #pragma unroll
    for (int k = 1; k < 8; ++k)
      #pragma unroll
      for (int i = 0; i < 8; ++i) {
        float v = e[8 * k + i]; float q = v * v;
        asm volatile("" : "+v"(q)); r[i] += q;
      }
    e2[j] = ((r[0] + r[1]) + (r[2] + r[3])) + ((r[4] + r[5]) + (r[6] + r[7]));
  }
}

// ---- fused: z stage + split-to-regs + z2 + MFMA distance + flags (r15) ----
__global__ __launch_bounds__(256, 4) void k_dist(const float* __restrict__ z,
    const short* __restrict__ cbfrag, const float* __restrict__ e2g,
    float* __restrict__ z2g, float* __restrict__ idxf, int* __restrict__ flag) {
  __shared__ float4 smem4[2320];                 // 37120 B
  short* lBs = (short*)smem4;
  float* e2l = (float*)(smem4 + 2048);
  float* z2l = (float*)(smem4 + 2304);
  float (*lzf)[65] = (float(*)[65])smem4;

  const int t = threadIdx.x, w = t >> 6, lane = t & 63;
  const int row0 = blockIdx.x * 64;

  gld16(e2g + w * 256 + lane * 4, e2l + w * 256);

  const int rl = w * 16 + (lane & 15);
  const int n0 = row0 + rl;
  const int bb = n0 >> 10, hw = n0 & 1023;
  const float* __restrict__ zp = z + (size_t)bb * 65536 + hw;
  const int k0 = (lane >> 4) * 8;
  #pragma unroll
  for (int ks = 0; ks < 2; ++ks)
    #pragma unroll
    for (int i = 0; i < 8; ++i)
      lzf[ks * 32 + k0 + i][rl] = zp[(size_t)(ks * 32 + k0 + i) << 10];
  __syncthreads();

  short8v a[2][2];
  #pragma unroll
  for (int ks = 0; ks < 2; ++ks) {
    short h[8], lo[8];
    #pragma unroll
    for (int i = 0; i < 8; ++i) {
      const float v = lzf[ks * 32 + k0 + i][rl];
      const unsigned hb = bf16_rne(v);
      const float res = v - __uint_as_float(hb << 16);
      h[i] = (short)hb; lo[i] = (short)bf16_rne(res);
    }
    a[0][ks] = *(short8v*)h;
    a[1][ks] = *(short8v*)lo;
  }
  if (t < 64) {
    float r[8];
    #pragma unroll
    for (int i = 0; i < 8; ++i) {
      const float v = lzf[i][t];
      float q = v * v; asm volatile("" : "+v"(q)); r[i] = q;
    }
    #pragma unroll
    for (int k = 1; k < 8; ++k)
      #pragma unroll
      for (int i = 0; i < 8; ++i) {
        const float v = lzf[8 * k + i][t];
        float q = v * v; asm volatile("" : "+v"(q)); r[i] += q;
      }
    const float z2v = ((r[0] + r[1]) + (r[2] + r[3])) + ((r[4] + r[5]) + (r[6] + r[7]));
    z2g[row0 + t] = z2v;
    z2l[t] = z2v;
  }
  __syncthreads();

  #pragma unroll
  for (int i = 0; i < 4; ++i) {
    const int s = w * 4 + i;
    gld16(cbfrag + s * 512 + lane * 8, lBs + s * 512);
  }
  float z2r[4];
  #pragma unroll
  for (int reg = 0; reg < 4; ++reg)
    z2r[reg] = z2l[w * 16 + (lane >> 4) * 4 + reg];
  float Tm[4], Ts[4]; int Tb[4];
  #pragma unroll
  for (int reg = 0; reg < 4; ++reg) { Tm[reg] = 1e30f; Ts[reg] = 1e30f; Tb[reg] = 0; }
  __syncthreads();

  int buf = 0;
  for (int c = 0; c < 16; ++c) {
    if (c < 15) {
      #pragma unroll
      for (int i = 0; i < 4; ++i) {
        const int s = w * 4 + i;
        gld16(cbfrag + (size_t)(c + 1) * 8192 + s * 512 + lane * 8,
              lBs + (buf ^ 1) * 8192 + s * 512);
      }
    }
    #pragma unroll 1
    for (int ctl = 0; ctl < 4; ++ctl) {
      short8v bfr[2][2];
      #pragma unroll
      for (int hl = 0; hl < 2; ++hl)
        #pragma unroll
        for (int ks = 0; ks < 2; ++ks)
          bfr[hl][ks] = *(const short8v*)(lBs + buf * 8192 +
              (ctl * 4 + hl * 2 + ks) * 512 + lane * 8);

      f32x4 acc = (f32x4)(0.0f);
      #pragma unroll
      for (int p = 0; p < 3; ++p) {
        const int pa = (p == 2) ? 1 : 0;
        const int pb = (p == 1) ? 1 : 0;
        #pragma unroll
        for (int ks = 0; ks < 2; ++ks)
          acc = __builtin_amdgcn_mfma_f32_16x16x32_bf16(a[pa][ks], bfr[pb][ks], acc, 0, 0, 0);
      }
      const int j = c * 64 + ctl * 16 + (lane & 15);
      const float e2v = e2l[j];
      #pragma unroll
      for (int reg = 0; reg < 4; ++reg) {
        const float dd = (z2r[reg] + e2v) - 2.0f * acc[reg];
        if (dd < Tm[reg]) { Ts[reg] = Tm[reg]; Tm[reg] = dd; Tb[reg] = j; }
        else { Ts[reg] = fminf(Ts[reg], dd); }
      }
    }
    __syncthreads();
    buf ^= 1;
  }

  #pragma unroll
  for (int reg = 0; reg < 4; ++reg) {
    float m = Tm[reg], s = Ts[reg]; int bi = Tb[reg];
    #pragma unroll
    for (int off = 1; off < 16; off <<= 1) {
      const float om = __shfl_xor(m, off, 64);
      const float os = __shfl_xor(s, off, 64);
      const int   oi = __shfl_xor(bi, off, 64);
      if (om < m || (om == m && oi < bi)) { s = fminf(m, os); m = om; bi = oi; }
      else { s = fminf(s, om); }
    }
    if ((lane & 15) == 0) {
      const int n = row0 + w * 16 + (lane >> 4) * 4 + reg;
      idxf[n] = (float)bi;
      flag[n] = (s - m < ERR_GAP) ? 1 : 0;
    }
  }
}

// ---- exact rescore v3: codebook amortized across the block's flagged rows ----
// cb traffic: 256KB per BLOCK (was per ROW — the ~73us L2 hog). Each thread
// holds one cb row in 16 static float4 regs per code-group; z-rows staged in
// LDS (broadcast reads). Chain = verbatim sequential ascending-k fmaf;
// lexicographic (d,j) reduce over all 1024 codes == numpy first-index argmin.
__global__ __launch_bounds__(256, 2) void k_exact3(const float* __restrict__ z,
    const float* __restrict__ cb, const float* __restrict__ e2g,
    const float* __restrict__ z2g, const int* __restrict__ flag,
    float* __restrict__ idxf) {
  __shared__ float zAll[64][64];     // 16 KB (worst case: all 64 rows flagged)
  __shared__ float z2All[64];
  __shared__ int   rowIdx[64];
  __shared__ float bestM[64];
  __shared__ int   bestI[64];
  __shared__ float wredM[4];
  __shared__ int   wredI[4];
  __shared__ unsigned long long maskS;
  const int t = threadIdx.x, w = t >> 6, lane = t & 63;
  const int row0 = blockIdx.x * 64;

  if (t < 64) {
    const unsigned long long mk = __ballot(flag[row0 + lane] != 0);
    if (lane == 0) maskS = mk;
  }
  __syncthreads();
  const unsigned long long mask0 = maskS;
  if (mask0 == 0) return;                       // uniform exit
  const int nrows = __popcll(mask0);

  if (t < 64 && (mask0 >> t) & 1ull) {
    const int rank = __popcll(mask0 & ((1ull << t) - 1ull));
    rowIdx[rank] = row0 + t;
  }
  __syncthreads();
  for (int i = w; i < nrows; i += 4) {          // stage z rows + z2
    const int n = rowIdx[i];
    const int b = n >> 10, hw = n & 1023;
    zAll[i][lane] = z[(size_t)b * 65536 + ((size_t)lane << 10) + hw];
    if (lane == 0) z2All[i] = z2g[n];
  }
  if (t < 64) { bestM[t] = 1e30f; bestI[t] = 0; }
  __syncthreads();

  #pragma unroll 1
  for (int g = 0; g < 4; ++g) {
    const int j = g * 256 + t;                  // this thread's code
    float4 er4[16];                             // cb row j in regs (static idx)
    const float4* __restrict__ cbp = (const float4*)(cb + (size_t)j * ED);
    #pragma unroll
    for (int q = 0; q < 16; ++q) er4[q] = cbp[q];
    const float e2v = e2g[j];
    #pragma unroll 1
    for (int i = 0; i < nrows; ++i) {
      float a = 0.f;
      #pragma unroll
      for (int q = 0; q < 16; ++q) {            // k ascending: verbatim chain
        a = fmaf(zAll[i][4 * q + 0], er4[q].x, a);
        a = fmaf(zAll[i][4 * q + 1], er4[q].y, a);
        a = fmaf(zAll[i][4 * q + 2], er4[q].z, a);
        a = fmaf(zAll[i][4 * q + 3], er4[q].w, a);
      }
      float d = (z2All[i] + e2v) - 2.0f * a;
      int bi = j;
      #pragma unroll
      for (int off = 1; off < 64; off <<= 1) {  // wave lex-reduce
        const float om = __shfl_xor(d, off, 64);
        const int   oi = __shfl_xor(bi, off, 64);
        if (om < d || (om == d && oi < bi)) { d = om; bi = oi; }
      }
      if (lane == 0) { wredM[w] = d; wredI[w] = bi; }
      __syncthreads();
      if (t == 0) {
        float m = bestM[i]; int mi = bestI[i];
        #pragma unroll
        for (int ww = 0; ww < 4; ++ww)
          if (wredM[ww] < m || (wredM[ww] == m && wredI[ww] < mi)) {
            m = wredM[ww]; mi = wredI[ww];
          }
        bestM[i] = m; bestI[i] = mi;
      }
      __syncthreads();                          // protect wred before reuse
    }
  }
  if (t < nrows) idxf[rowIdx[t]] = (float)bestI[t];
}

// ---- z_q gather + loss partial + fused one-hot scatter ----
__global__ __launch_bounds__(256) void k_zq(const float* __restrict__ z,
    const float* __restrict__ cb, const float* __restrict__ idxf,
    float* __restrict__ zq, float* __restrict__ partial, float* __restrict__ me) {
  float s = 0.f;
  #pragma unroll 1
  for (int it = 0; it < 8; ++it) {
    const int o = (it * 2048 + blockIdx.x) * 256 + threadIdx.x;
    const int b = o >> 16;
    const int d = (o >> 10) & 63;
    const int hw = o & 1023;
    const int n = (b << 10) + hw;
    const int idx = (int)idxf[n];
    const float v = cb[(size_t)idx * ED + d];
    zq[o] = v;
    if (d == 0) me[(size_t)n * NE + idx] = 1.0f;
    const float diff = z[o] - v;
    s = fmaf(diff, diff, s);
  }
  #pragma unroll
  for (int off = 32; off > 0; off >>= 1) s += __shfl_xor(s, off, 64);
  __shared__ float sh[4];
  if ((threadIdx.x & 63) == 0) sh[threadIdx.x >> 6] = s;
  __syncthreads();
  if (threadIdx.x == 0)
    partial[blockIdx.x] = (sh[0] + sh[1]) + (sh[2] + sh[3]);
}

__global__ void k_loss(const float* __restrict__ partial, float* __restrict__ out0) {
  const int t = threadIdx.x;
  double s = 0.0;
  #pragma unroll
  for (int k = 0; k < 8; ++k) s += (double)partial[t + (k << 8)];
  #pragma unroll
  for (int off = 32; off > 0; off >>= 1) s += __shfl_xor(s, off, 64);
  __shared__ double sh[4];
  if ((t & 63) == 0) sh[t >> 6] = s;
  __syncthreads();
  if (t == 0)
    out0[0] = (float)(1.25 * ((sh[0] + sh[1]) + (sh[2] + sh[3])) / 4194304.0);
}

extern "C" void kernel_launch(void* const* d_in, const int* in_sizes, int n_in,
                              void* d_out, int out_size, void* d_ws, size_t ws_size,
                              hipStream_t stream) {
  const float* z  = (const float*)d_in[0];
  const float* cb = (const float*)d_in[1];
  float* out  = (float*)d_out;
  float* zq   = out + OFF_ZQ;
  float* me   = out + OFF_ME;
  float* idxf = out + OFF_IDX;
  float* sbase = out + 4;
  short* cbfrag = (short*)(sbase + SC_CBF);
  float* z2     = sbase + SC_Z2;
  int*   flag   = (int*)(sbase + SC_FLAG);
  float* e2      = (float*)((char*)d_ws + 16);
  float* partial = (float*)((char*)d_ws + 4112);

  k_fill<<<2048, 256, 0, stream>>>(me);
  k_e2cb<<<16, 256, 0, stream>>>(cb, e2, cbfrag);
  k_dist<<<1024, 256, 0, stream>>>(z, cbfrag, e2, z2, idxf, flag);
  k_exact3<<<1024, 256, 0, stream>>>(z, cb, e2, z2, flag, idxf);
  k_zq<<<2048, 256, 0, stream>>>(z, cb, idxf, zq, partial, me);
  k_loss<<<1, 256, 0, stream>>>(partial, out);
}